// Round 1
// baseline (191.144 us; speedup 1.0000x reference)
//
#include <hip/hip_runtime.h>

typedef _Float16 half_t;
typedef _Float16 half8 __attribute__((ext_vector_type(8)));
typedef float f32x4 __attribute__((ext_vector_type(4)));

#define MFMA16(a, b, c) __builtin_amdgcn_mfma_f32_16x16x32_f16((a), (b), (c), 0, 0, 0)

// Problem constants
static constexpr int kM  = 512;     // queries per bh
static constexpr int kD  = 64;      // head dim
static constexpr int kKL = 2560;    // key length
// ws layout (in half elements), all 16B-aligned
static constexpr int WS_QS  = 0;                   // 32*512*64   = 1,048,576 (q * 0.125*log2e)
static constexpr int WS_KB  = 1048576;             // 32*2560*64  = 5,242,880
static constexpr int WS_VB  = WS_KB + 5242880;
static constexpr int WS_PET = WS_VB + 5242880;     // peT[l][d], 2048*64 = 131,072
// total = 11,665,408 halves = 23,330,816 bytes of d_ws

// ---------------- K1: f32 -> f16 convert (+ q pre-scale, pe transpose) ----------------
__global__ __launch_bounds__(256) void cvt_kernel(const float* __restrict__ q,
    const float* __restrict__ k, const float* __restrict__ v,
    const float* __restrict__ pe, half_t* __restrict__ ws) {
  int i = blockIdx.x * 256 + threadIdx.x;
  const float QS = 0.125f * 1.4426950408889634f;  // 1/sqrt(64) * log2(e)
  if (i < 262144) {
    float4 x = ((const float4*)q)[i];
    half_t* o = ws + WS_QS + i * 4;
    o[0] = (half_t)(x.x * QS); o[1] = (half_t)(x.y * QS);
    o[2] = (half_t)(x.z * QS); o[3] = (half_t)(x.w * QS);
  } else if (i < 262144 + 1310720) {
    int j = i - 262144;
    float4 x = ((const float4*)k)[j];
    half_t* o = ws + WS_KB + j * 4;
    o[0] = (half_t)x.x; o[1] = (half_t)x.y; o[2] = (half_t)x.z; o[3] = (half_t)x.w;
  } else if (i < 262144 + 2621440) {
    int j = i - (262144 + 1310720);
    float4 x = ((const float4*)v)[j];
    half_t* o = ws + WS_VB + j * 4;
    o[0] = (half_t)x.x; o[1] = (half_t)x.y; o[2] = (half_t)x.z; o[3] = (half_t)x.w;
  } else {
    int p = i - (262144 + 2621440);
    int l = p >> 6, d = p & 63;
    ws[WS_PET + l * 64 + d] = (half_t)pe[d * 2048 + l];   // transpose to peT[l][d]
  }
}

// ---------------- K2: fused banded flash attention ----------------
// grid = 1024 (bh x 16-row q-tile, XCD-swizzled), block = 256 (4 waves).
// Wave layout per 16x16 MFMA: c = lane&15, qd = lane>>4.
//   A-frag:  A[m=c][k=qd*8+j]   C/D: row = qd*4+reg, col = c
// Each wave handles a contiguous quarter of the 65 32-key tiles of the
// union window [m0, m0+2062]; merge across waves in the epilogue.
// Per-wave LDS (9728 B): Vt[64][40] f16 (5120) | peS[16][52] f32 (3328) | Pb[16][40] f16 (1280)
__global__ __launch_bounds__(256, 4) void attn_kernel(
    const half_t* __restrict__ ws, const float* __restrict__ cvp,
    float* __restrict__ out) {

  __shared__ __align__(16) char smem[39680];  // 4*9728 + 768 merge scalars

  const int tid  = threadIdx.x;
  const int lane = tid & 63;
  const int w    = tid >> 6;
  const int c    = lane & 15;
  const int qd   = lane >> 4;

  const int id = blockIdx.x;
  // id bits: [2:0]=bh>>2 (XCD), [7:3]=mt, [9:8]=bh&3  -> each XCD sees 4 bh values
  const int bh = ((id & 7) << 2) | (id >> 8);
  const int mt = (id >> 3) & 31;
  const int m0 = mt << 4;

  const float cvl = cvp[bh & 7] * 2048.0f - 2047.0f;  // mask = clamp((l + cvl)/64 + 1, 0, 1)

  const half_t* qs  = ws + WS_QS;
  const half_t* kb  = ws + WS_KB + bh * (kKL * kD);
  const half_t* vb  = ws + WS_VB + bh * (kKL * kD);
  const half_t* pet = ws + WS_PET;

  // Q A-fragments (row m0+c, k-chunks 0..31 / 32..63) — same frags feed S and PE MFMAs
  const half_t* qrow = qs + (bh * kM + m0 + c) * kD;
  const half8 aq0 = *(const half8*)(qrow + qd * 8);
  const half8 aq1 = *(const half8*)(qrow + 32 + qd * 8);

  char*   wbase = smem + w * 9728;
  half_t* Vt    = (half_t*)wbase;             // [d=64][k=32] pad-40, 80B rows
  float*  peS   = (float*)(wbase + 5120);     // [r=16][li=48] stride 52
  half_t* Pb    = (half_t*)(wbase + 8448);    // [m=16][k=32] pad-40, 80B rows

  float cold[4], zal[4], zm[4];
  f32x4 o0 = {0,0,0,0}, o1 = {0,0,0,0}, o2 = {0,0,0,0}, o3 = {0,0,0,0};
#pragma unroll
  for (int r = 0; r < 4; ++r) { cold[r] = -1e30f; zal[r] = 0.0f; zm[r] = 0.0f; }

  const int t0 = (w * 65) >> 2;          // 0,16,32,48
  const int t1 = ((w + 1) * 65) >> 2;    // 16,32,48,65

  const int np  = (lane >> 2) & 15;      // V-stage: key pair index
  const int d4b = lane & 3;              // V-stage: d quad base

  for (int t = t0; t < t1; ++t) {
    const int rel0 = t * 32;
    const int n0   = m0 + rel0;          // absolute key base for this tile

    // ---- V global loads (rows n0+2np, n0+2np+1; 4 halves along d each) ----
    int r0 = n0 + 2 * np; if (r0 > kKL - 1) r0 = kKL - 1;
    int r1 = n0 + 2 * np + 1; if (r1 > kKL - 1) r1 = kKL - 1;
    ushort4 vA[4], vB[4];
#pragma unroll
    for (int it = 0; it < 4; ++it) {
      const int dq = d4b + it * 4;
      vA[it] = *(const ushort4*)(vb + r0 * kD + dq * 4);
      vB[it] = *(const ushort4*)(vb + r1 * kD + dq * 4);
    }

    // ---- K B-fragments straight from global (row n, k-chunk = d) ----
    int kr0 = n0 + c;      if (kr0 > kKL - 1) kr0 = kKL - 1;
    int kr1 = n0 + 16 + c; if (kr1 > kKL - 1) kr1 = kKL - 1;
    const half8 bk00 = *(const half8*)(kb + kr0 * kD + qd * 8);
    const half8 bk01 = *(const half8*)(kb + kr0 * kD + 32 + qd * 8);
    const half8 bk10 = *(const half8*)(kb + kr1 * kD + qd * 8);
    const half8 bk11 = *(const half8*)(kb + kr1 * kD + 32 + qd * 8);

    // ---- PE score tiles: peS[r][li] for l = (rel0-16)+li, li in [0,48) ----
    const int lbase = rel0 - 16;
    f32x4 pacc[3];
#pragma unroll
    for (int pt = 0; pt < 3; ++pt) {
      int l = lbase + pt * 16 + c;
      if (l < 0) l = 0; if (l > 2047) l = 2047;       // clamped cols are never read as valid
      const half8 b0 = *(const half8*)(pet + l * kD + qd * 8);
      const half8 b1 = *(const half8*)(pet + l * kD + 32 + qd * 8);
      f32x4 acc = {0,0,0,0};
      acc = MFMA16(aq0, b0, acc);
      acc = MFMA16(aq1, b1, acc);
      pacc[pt] = acc;
    }

    // ---- wait prior-iter LDS reads retired, then write peS + Vt ----
    asm volatile("s_waitcnt lgkmcnt(0)" ::: "memory");
#pragma unroll
    for (int pt = 0; pt < 3; ++pt)
#pragma unroll
      for (int reg = 0; reg < 4; ++reg)
        peS[(qd * 4 + reg) * 52 + pt * 16 + c] = pacc[pt][reg];

#pragma unroll
    for (int it = 0; it < 4; ++it) {
      const int dq = d4b + it * 4;
      const unsigned short* a = (const unsigned short*)&vA[it];
      const unsigned short* b = (const unsigned short*)&vB[it];
#pragma unroll
      for (int j = 0; j < 4; ++j) {
        unsigned int val = (unsigned int)a[j] | ((unsigned int)b[j] << 16);
        *(unsigned int*)((char*)Vt + (dq * 4 + j) * 80 + np * 4) = val;  // Vt[d][2np,2np+1]
      }
    }

    // ---- S = Q·K^T (2 column tiles) ----
    f32x4 s0acc = {0,0,0,0}, s1acc = {0,0,0,0};
    s0acc = MFMA16(aq0, bk00, s0acc); s0acc = MFMA16(aq1, bk01, s0acc);
    s1acc = MFMA16(aq0, bk10, s1acc); s1acc = MFMA16(aq1, bk11, s1acc);

    asm volatile("s_waitcnt lgkmcnt(0)" ::: "memory");

    // ---- online softmax + mask, write P (masked, exp2-domain) ----
    float al[4];
#pragma unroll
    for (int reg = 0; reg < 4; ++reg) {
      const int r  = qd * 4 + reg;
      const int l0 = rel0 + c - r;       // relative pos for col tile 0
      const int l1 = l0 + 16;
      const float b0 = peS[r * 52 + (c - r + 16)];
      const float b1 = peS[r * 52 + (c - r + 32)];
      float s0 = (l0 >= 0 && l0 < 2048) ? (s0acc[reg] + b0) : -1e30f;
      float s1 = (l1 >= 0 && l1 < 2048) ? (s1acc[reg] + b1) : -1e30f;
      float mx = fmaxf(s0, s1);
      mx = fmaxf(mx, __shfl_xor(mx, 1));
      mx = fmaxf(mx, __shfl_xor(mx, 2));
      mx = fmaxf(mx, __shfl_xor(mx, 4));
      mx = fmaxf(mx, __shfl_xor(mx, 8));
      const float cn    = fmaxf(cold[reg], mx);
      const float alpha = exp2f(cold[reg] - cn);
      cold[reg] = cn;
      const float p0 = exp2f(s0 - cn);   // invalid -> exp2(-huge) = 0
      const float p1 = exp2f(s1 - cn);
      const float mk0 = fminf(fmaxf(((float)l0 + cvl) * 0.015625f + 1.0f, 0.0f), 1.0f);
      const float mk1 = fminf(fmaxf(((float)l1 + cvl) * 0.015625f + 1.0f, 0.0f), 1.0f);
      const float pm0 = p0 * mk0, pm1 = p1 * mk1;
      zal[reg] = zal[reg] * alpha + p0 + p1;
      zm[reg]  = zm[reg]  * alpha + pm0 + pm1;
      al[reg]  = alpha;
      Pb[r * 40 + c]      = (half_t)pm0;
      Pb[r * 40 + 16 + c] = (half_t)pm1;
    }

    asm volatile("s_waitcnt lgkmcnt(0)" ::: "memory");

    // ---- PV: O[m][d] += P(16x32) · V(32x64) ----
    const half8 ap  = *(const half8*)(Pb + c * 40 + qd * 8);
    const half8 bv0 = *(const half8*)(Vt + (c) * 40 + qd * 8);
    const half8 bv1 = *(const half8*)(Vt + (16 + c) * 40 + qd * 8);
    const half8 bv2 = *(const half8*)(Vt + (32 + c) * 40 + qd * 8);
    const half8 bv3 = *(const half8*)(Vt + (48 + c) * 40 + qd * 8);
#pragma unroll
    for (int reg = 0; reg < 4; ++reg) {
      o0[reg] *= al[reg]; o1[reg] *= al[reg]; o2[reg] *= al[reg]; o3[reg] *= al[reg];
    }
    o0 = MFMA16(ap, bv0, o0);
    o1 = MFMA16(ap, bv1, o1);
    o2 = MFMA16(ap, bv2, o2);
    o3 = MFMA16(ap, bv3, o3);
  }

  // ---- epilogue: reduce per-lane partial sums over the 16-lane group ----
#pragma unroll
  for (int reg = 0; reg < 4; ++reg) {
    zal[reg] += __shfl_xor(zal[reg], 1); zal[reg] += __shfl_xor(zal[reg], 2);
    zal[reg] += __shfl_xor(zal[reg], 4); zal[reg] += __shfl_xor(zal[reg], 8);
    zm[reg]  += __shfl_xor(zm[reg], 1);  zm[reg]  += __shfl_xor(zm[reg], 2);
    zm[reg]  += __shfl_xor(zm[reg], 4);  zm[reg]  += __shfl_xor(zm[reg], 8);
  }
  float* mrgC = (float*)(smem + 38912);
  float* mrgA = mrgC + 64;
  float* mrgM = mrgC + 128;
  if (c == 0) {
#pragma unroll
    for (int reg = 0; reg < 4; ++reg) {
      const int r = qd * 4 + reg;
      mrgC[w * 16 + r] = cold[reg];
      mrgA[w * 16 + r] = zal[reg];
      mrgM[w * 16 + r] = zm[reg];
    }
  }
  float* Ow = (float*)wbase;  // overlay Vt area: [r=16] stride 68 f32 (4352B < 5120B)
#pragma unroll
  for (int reg = 0; reg < 4; ++reg) {
    const int r = qd * 4 + reg;
    Ow[r * 68 + c]      = o0[reg];
    Ow[r * 68 + 16 + c] = o1[reg];
    Ow[r * 68 + 32 + c] = o2[reg];
    Ow[r * 68 + 48 + c] = o3[reg];
  }
  __syncthreads();

  // ---- merge the 4 wave partials, final normalize (exact ref semantics) ----
  const int dd = tid & 63;
  const int rb = tid >> 6;
#pragma unroll
  for (int rr = 0; rr < 4; ++rr) {
    const int r = rb * 4 + rr;
    float C = mrgC[r];
    C = fmaxf(C, mrgC[16 + r]); C = fmaxf(C, mrgC[32 + r]); C = fmaxf(C, mrgC[48 + r]);
    float za = 0.0f, zmm = 0.0f, ov = 0.0f;
#pragma unroll
    for (int ww = 0; ww < 4; ++ww) {
      const float a = exp2f(mrgC[ww * 16 + r] - C);
      za  += a * mrgA[ww * 16 + r];
      zmm += a * mrgM[ww * 16 + r];
      ov  += a * ((float*)(smem + ww * 9728))[r * 68 + dd];
    }
    out[(bh * kM + m0 + r) * kD + dd] = ov / (zmm + 1e-8f * za);
  }
}

extern "C" void kernel_launch(void* const* d_in, const int* in_sizes, int n_in,
                              void* d_out, int out_size, void* d_ws, size_t ws_size,
                              hipStream_t stream) {
  (void)in_sizes; (void)n_in; (void)out_size; (void)ws_size;
  const float* q  = (const float*)d_in[0];
  const float* k  = (const float*)d_in[1];
  const float* v  = (const float*)d_in[2];
  const float* pe = (const float*)d_in[3];
  const float* cv = (const float*)d_in[4];
  half_t* ws = (half_t*)d_ws;   // needs 23,330,816 bytes
  float* out = (float*)d_out;

  cvt_kernel<<<11776, 256, 0, stream>>>(q, k, v, pe, ws);   // 11776*256 = 3,014,656 items
  attn_kernel<<<1024, 256, 0, stream>>>(ws, cv, out);
}